// Round 17
// baseline (181.975 us; speedup 1.0000x reference)
//
#include <hip/hip_runtime.h>

constexpr int BB = 16;        // batch
constexpr int HH = 512;
constexpr int WW = 512;
constexpr int HW = HH * WW;   // 262144 = 2^18
constexpr int NP1 = BB * HW;  // one single-channel plane (elements)

using half_t = _Float16;
using half2v = __attribute__((ext_vector_type(2))) _Float16;
using half8v = __attribute__((ext_vector_type(8))) _Float16;

__device__ __forceinline__ half2v hfma2(half2v a, half2v b, half2v c) {
#if __has_builtin(__builtin_elementwise_fma)
    return __builtin_elementwise_fma(a, b, c);
#else
    return a * b + c;
#endif
}

// 11-tap Gaussian, theta=1, normalized (== normal pdf values to ~1e-8 rel).
__device__ constexpr float GK[11] = {
    1.4867195147342977e-06f,
    1.3383022576488537e-04f,
    4.4318484119380075e-03f,
    5.3990966513188063e-02f,
    2.4197072451914337e-01f,
    3.9894228040143270e-01f,
    2.4197072451914337e-01f,
    5.3990966513188063e-02f,
    4.4318484119380075e-03f,
    1.3383022576488537e-04f,
    1.4867195147342977e-06f,
};
// prefix sums of the smallest taps: PFX[k] = GK[0]+..+GK[k-1]
__device__ constexpr float PFX[6] = {
    0.0f,
    1.4867195147342977e-06f,
    1.3531694527962e-04f,
    4.5671653572176e-03f,
    5.8558131870406e-02f,
    3.0052885638955e-01f,
};

// blur(ones) separable factor with zero padding
__device__ __forceinline__ float edgeS(int i) {
    float s = 1.f;
    if (i < 5)   s -= PFX[5 - i];
    if (i > 506) s -= PFX[i - 506];
    return s;
}

__device__ __forceinline__ float sig1(float d) {
    d = fminf(fmaxf(d, -30.f), 30.f);
    float e = __expf(d);
    return e * __builtin_amdgcn_rcpf(1.f + e);
}

// Packed fp16 hblur for px pair (x0,x0+1) of LDS row vr (layout: zeros [0,6),
// data px p at 6+p, zeros [518,524)). Proven in round 16.
__device__ __forceinline__ half2v hblur_pk(const half_t* vr, int tid) {
    const unsigned int* vd = (const unsigned int*)vr;
    unsigned int D[7];
#pragma unroll
    for (int k = 0; k < 7; ++k) D[k] = vd[tid + k];
    half2v m01 = half2v{(half_t)0.f, (half_t)0.f};
#pragma unroll
    for (int t = 0; t < 11; ++t) {
        unsigned int P;
        if (t & 1) P = D[(t + 1) >> 1];
        else       P = (D[t >> 1] >> 16) | (D[(t >> 1) + 1] << 16);
        half2v Ph = __builtin_bit_cast(half2v, P);
        half_t kh = (half_t)GK[t];
        half2v kv = half2v{kh, kh};
        m01 = hfma2(kv, Ph, m01);
    }
    return m01;
}

// ---------------------------------------------------------------------------
// Kernel 1: 3x3 conv (round-13 proven) + flags zeroing (blocks 0,1).
// Writes fp16 u0, du, q0 = sigmoid(du).
// ---------------------------------------------------------------------------
__global__ __launch_bounds__(256) void conv3x3_duq(
    const float* __restrict__ x, const float* __restrict__ w,
    const float* __restrict__ bias, half_t* __restrict__ u0p,
    half_t* __restrict__ dup, half_t* __restrict__ q0p,
    int* __restrict__ flags)
{
    int bid = blockIdx.x;
    if (bid < 2) flags[bid * 256 + threadIdx.x] = 0;   // 512 flags

    int sb  = (bid & 7) * 128 + (bid >> 3);     // grid 1024, bijective
    int t   = sb * 256 + threadIdx.x;
    int b   = t >> 14;
    int rem = t & 16383;
    int y0  = (rem >> 6) << 1;
    int xs  = (rem & 63) << 3;

    float W[54];
#pragma unroll
    for (int i = 0; i < 13; ++i)
        *(float4*)&W[4 * i] = *(const float4*)(w + 4 * i);
    W[52] = w[52];
    W[53] = w[53];
    float b0 = bias[0], b1 = bias[1];

    float acc0[2][8], acc1[2][8];
#pragma unroll
    for (int r = 0; r < 2; ++r)
#pragma unroll
        for (int j = 0; j < 8; ++j) { acc0[r][j] = b0; acc1[r][j] = b1; }

    const float* xb = x + (size_t)b * 3 * HW;
#pragma unroll
    for (int ci = 0; ci < 3; ++ci) {
        const float* xc = xb + ci * HW;
#pragma unroll
        for (int iy = 0; iy < 4; ++iy) {
            int yy = y0 - 1 + iy;
            if (yy < 0 || yy >= HH) continue;   // uniform
            const float* r = xc + yy * WW;
            float4 cA = *(const float4*)(r + xs);
            float4 cB = *(const float4*)(r + xs + 4);
            float l  = (xs > 0)      ? r[xs - 1] : 0.f;
            float rr = (xs < WW - 8) ? r[xs + 8] : 0.f;
            float v[10] = {l, cA.x, cA.y, cA.z, cA.w,
                           cB.x, cB.y, cB.z, cB.w, rr};
#pragma unroll
            for (int orow = 0; orow < 2; ++orow) {
                int kh = iy - orow;
                if (kh < 0 || kh > 2) continue;
                float w00 = W[ci * 9 + kh * 3 + 0];
                float w01 = W[ci * 9 + kh * 3 + 1];
                float w02 = W[ci * 9 + kh * 3 + 2];
                float w10 = W[27 + ci * 9 + kh * 3 + 0];
                float w11 = W[27 + ci * 9 + kh * 3 + 1];
                float w12 = W[27 + ci * 9 + kh * 3 + 2];
#pragma unroll
                for (int j = 0; j < 8; ++j) {
                    acc0[orow][j] = fmaf(w00, v[j],
                                    fmaf(w01, v[j + 1],
                                    fmaf(w02, v[j + 2], acc0[orow][j])));
                    acc1[orow][j] = fmaf(w10, v[j],
                                    fmaf(w11, v[j + 1],
                                    fmaf(w12, v[j + 2], acc1[orow][j])));
                }
            }
        }
    }
#pragma unroll
    for (int orow = 0; orow < 2; ++orow) {
        size_t o = (size_t)b * HW + (size_t)(y0 + orow) * WW + xs;
        half8v h0, h1, hq;
#pragma unroll
        for (int j = 0; j < 8; ++j) {
            float du = acc1[orow][j] - acc0[orow][j];
            h0[j] = (half_t)acc0[orow][j];
            h1[j] = (half_t)du;
            hq[j] = (half_t)sig1(du);
        }
        *(half8v*)(u0p + o) = h0;
        *(half8v*)(dup + o) = h1;
        *(half8v*)(q0p + o) = hq;
    }
}

// ---------------------------------------------------------------------------
// Kernel 2: persistent mega-kernel — all 5 CRF iterations + epilogue.
// Grid 512 = 16 images x 32 tiles of 16 rows. 256 threads x 2 px.
// Own q/du in registers; per iteration publish own 16 rows, release-store
// flags[tile]=j (agent scope), spin-acquire neighbors' flags >= j-1, read
// only the 10 halo rows from global. Gate invariant: a neighbor cannot be
// >1 iteration ahead on the buffer I'm reading, so qA/qB double-buffering
// is race-free. Co-residency: needs >= 2 blocks/CU; kernel uses ~17KB LDS
// and ~110 VGPR -> >= 4 blocks/CU capacity, grid 512 = 2/CU. No grid sync.
// ---------------------------------------------------------------------------
__global__ __launch_bounds__(256) void crf_mega(
    const half_t* __restrict__ q0p, const half_t* __restrict__ dup,
    const half_t* __restrict__ u0p, half_t* __restrict__ qA,
    half_t* __restrict__ qB, float* __restrict__ outp,
    int* flags)
{
    __shared__ half_t v[16][528];

    int bid  = blockIdx.x;
    int tile = (bid & 7) * 64 + (bid >> 3);    // grid 512, bijective
    int b    = tile >> 5;                      // 32 tiles / image
    int yt   = tile & 31;
    int y0   = yt << 4;                        // 16 owned rows
    int tid  = threadIdx.x;
    int x0   = tid << 1;

    if (tid < 6) {
#pragma unroll
        for (int r = 0; r < 16; ++r) {
            v[r][tid] = (half_t)0.f;
            v[r][518 + tid] = (half_t)0.f;
        }
    }

    size_t pb = (size_t)b * HW + x0;
    float SxA = edgeS(x0), SxB = edgeS(x0 + 1);
    bool has_up = (yt > 0), has_dn = (yt < 31);

    // own state in registers
    half2v q[16], du[16];
#pragma unroll
    for (int r = 0; r < 16; ++r) {
        size_t po = pb + (size_t)(y0 + r) * WW;
        q[r]  = *(const half2v*)(q0p + po);
        du[r] = *(const half2v*)(dup + po);
    }

    for (int j = 1; j <= 5; ++j) {
        if (j >= 2) {
            if (tid == 0) {
                if (has_up)
                    while (__hip_atomic_load(&flags[tile - 1], __ATOMIC_ACQUIRE,
                                             __HIP_MEMORY_SCOPE_AGENT) < j - 1)
                        __builtin_amdgcn_s_sleep(1);
                if (has_dn)
                    while (__hip_atomic_load(&flags[tile + 1], __ATOMIC_ACQUIRE,
                                             __HIP_MEMORY_SCOPE_AGENT) < j - 1)
                        __builtin_amdgcn_s_sleep(1);
            }
            __syncthreads();
        }

        const half_t* hs = (j == 1) ? q0p : ((j & 1) ? qB : qA);

        // vblur: own rows from regs, 10 halo rows from global
        half2v acc[16];
#pragma unroll
        for (int r = 0; r < 16; ++r) acc[r] = half2v{(half_t)0.f, (half_t)0.f};
#pragma unroll
        for (int i = 0; i < 26; ++i) {         // input rows y0-5 .. y0+20
            int yy = y0 + i - 5;
            if (yy < 0 || yy >= HH) continue;  // uniform
            half2v qv;
            if (i >= 5 && i < 21) qv = q[i - 5];
            else qv = *(const half2v*)(hs + pb + (size_t)yy * WW);
#pragma unroll
            for (int r = 0; r < 16; ++r) {
                int dt = i - r;
                if (dt < 0 || dt > 10) continue;   // compile-time
                half_t kh = (half_t)GK[dt];
                half2v kv = half2v{kh, kh};
                acc[r] = hfma2(kv, qv, acc[r]);
            }
        }

        __syncthreads();                       // prev hblur LDS reads done
#pragma unroll
        for (int r = 0; r < 16; ++r)
            *(half2v*)(&v[r][6 + x0]) = acc[r];
        __syncthreads();

        if (j < 5) {
            half_t* dst = (j & 1) ? qA : qB;
#pragma unroll
            for (int r = 0; r < 16; ++r) {
                int yy = y0 + r;
                float Sy = edgeS(yy);
                half2v m01h = hblur_pk(&v[r][0], tid);
                float m0 = (float)m01h[0], m1 = (float)m01h[1];
                float d0 = (float)du[r][0] + fmaf(2.f, m0, -(SxA * Sy));
                float d1 = (float)du[r][1] + fmaf(2.f, m1, -(SxB * Sy));
                half2v hq;
                hq[0] = (half_t)sig1(d0);
                hq[1] = (half_t)sig1(d1);
                q[r] = hq;
                *(half2v*)(dst + pb + (size_t)yy * WW) = hq;
            }
            __syncthreads();                   // all publish writes issued
            if (tid == 0) {
                __threadfence();
                __hip_atomic_store(&flags[tile], j, __ATOMIC_RELEASE,
                                   __HIP_MEMORY_SCOPE_AGENT);
            }
        } else {
            // final: epilogue
#pragma unroll
            for (int r = 0; r < 16; ++r) {
                int yy = y0 + r;
                float Sy = edgeS(yy);
                half2v m01h = hblur_pk(&v[r][0], tid);
                float m0 = (float)m01h[0], m1 = (float)m01h[1];
                size_t po = pb + (size_t)yy * WW;
                half2v u0v = *(const half2v*)(u0p + po);
                float ua = (float)u0v[0], ub = (float)u0v[1];
                float dua = (float)du[r][0], dub = (float)du[r][1];
                float S0 = SxA * Sy, S1 = SxB * Sy;
                size_t oo = (size_t)b * 2 * HW + (size_t)yy * WW + x0;
                *(float2*)(outp + oo)      = make_float2(ua + (S0 - m0),
                                                         ub + (S1 - m1));
                *(float2*)(outp + oo + HW) = make_float2((ua + dua) + m0,
                                                         (ub + dub) + m1);
            }
        }
    }
}

extern "C" void kernel_launch(void* const* d_in, const int* in_sizes, int n_in,
                              void* d_out, int out_size, void* d_ws, size_t ws_size,
                              hipStream_t stream) {
    const float* x    = (const float*)d_in[0];   // (16,3,512,512)
    const float* w    = (const float*)d_in[1];   // (2,3,3,3)
    const float* bias = (const float*)d_in[2];   // (2,)

    float*  out = (float*)d_out;                 // (16,2,512,512) fp32
    half_t* u0p = (half_t*)d_ws;                 // 8.4 MB
    half_t* dup = u0p + NP1;                     // 8.4 MB
    half_t* q0p = dup + NP1;                     // 8.4 MB
    half_t* qA  = q0p + NP1;                     // 8.4 MB
    half_t* qB  = qA + NP1;                      // 8.4 MB
    int*   flags = (int*)(qB + NP1);             // 512 ints

    conv3x3_duq<<<1024, 256, 0, stream>>>(x, w, bias, u0p, dup, q0p, flags);
    crf_mega<<<512, 256, 0, stream>>>(q0p, dup, u0p, qA, qB, out, flags);
}

// Round 18
// 67.588 us; speedup vs baseline: 2.6924x; 2.6924x over previous
//
#include <hip/hip_runtime.h>

constexpr int BB = 16;        // batch
constexpr int HH = 512;
constexpr int WW = 512;
constexpr int HW = HH * WW;   // 262144 = 2^18
constexpr int NP1 = BB * HW;  // one single-channel plane (elements)

using half_t = _Float16;
using half2v = __attribute__((ext_vector_type(2))) _Float16;
using half8v = __attribute__((ext_vector_type(8))) _Float16;

__device__ __forceinline__ half2v hfma2(half2v a, half2v b, half2v c) {
#if __has_builtin(__builtin_elementwise_fma)
    return __builtin_elementwise_fma(a, b, c);
#else
    return a * b + c;
#endif
}

// 11-tap Gaussian, theta=1, normalized (== normal pdf values to ~1e-8 rel).
__device__ constexpr float GK[11] = {
    1.4867195147342977e-06f,
    1.3383022576488537e-04f,
    4.4318484119380075e-03f,
    5.3990966513188063e-02f,
    2.4197072451914337e-01f,
    3.9894228040143270e-01f,
    2.4197072451914337e-01f,
    5.3990966513188063e-02f,
    4.4318484119380075e-03f,
    1.3383022576488537e-04f,
    1.4867195147342977e-06f,
};
// prefix sums of the smallest taps: PFX[k] = GK[0]+..+GK[k-1]
__device__ constexpr float PFX[6] = {
    0.0f,
    1.4867195147342977e-06f,
    1.3531694527962e-04f,
    4.5671653572176e-03f,
    5.8558131870406e-02f,
    3.0052885638955e-01f,
};

// blur(ones) separable factor with zero padding
__device__ __forceinline__ float edgeS(int i) {
    float s = 1.f;
    if (i < 5)   s -= PFX[5 - i];
    if (i > 506) s -= PFX[i - 506];
    return s;
}

__device__ __forceinline__ float sig1(float d) {
    d = fminf(fmaxf(d, -30.f), 30.f);
    float e = __expf(d);
    return e * __builtin_amdgcn_rcpf(1.f + e);
}

// Packed fp16 hblur for px pair (x0,x0+1) of LDS row vr (layout: zeros [0,6),
// data px p at 6+p, zeros [518,524)). Proven in round 16.
__device__ __forceinline__ half2v hblur_pk(const half_t* vr, int tid) {
    const unsigned int* vd = (const unsigned int*)vr;
    unsigned int D[7];
#pragma unroll
    for (int k = 0; k < 7; ++k) D[k] = vd[tid + k];
    half2v m01 = half2v{(half_t)0.f, (half_t)0.f};
#pragma unroll
    for (int t = 0; t < 11; ++t) {
        unsigned int P;
        if (t & 1) P = D[(t + 1) >> 1];
        else       P = (D[t >> 1] >> 16) | (D[(t >> 1) + 1] << 16);
        half2v Ph = __builtin_bit_cast(half2v, P);
        half_t kh = (half_t)GK[t];
        half2v kv = half2v{kh, kh};
        m01 = hfma2(kv, Ph, m01);
    }
    return m01;
}

// ---------------------------------------------------------------------------
// Kernel 1: 3x3 conv, C_in=3 -> C_out=2, SAME zero-pad (round-13 proven).
// 2 output rows x 8 px per thread. Writes fp16 u0, du, q0 = sigmoid(du).
// ---------------------------------------------------------------------------
__global__ __launch_bounds__(256) void conv3x3_duq(
    const float* __restrict__ x, const float* __restrict__ w,
    const float* __restrict__ bias, half_t* __restrict__ u0p,
    half_t* __restrict__ dup, half_t* __restrict__ q0p)
{
    int bid = blockIdx.x;
    int sb  = (bid & 7) * 128 + (bid >> 3);     // grid 1024, bijective
    int t   = sb * 256 + threadIdx.x;
    int b   = t >> 14;
    int rem = t & 16383;
    int y0  = (rem >> 6) << 1;
    int xs  = (rem & 63) << 3;

    float W[54];
#pragma unroll
    for (int i = 0; i < 13; ++i)
        *(float4*)&W[4 * i] = *(const float4*)(w + 4 * i);
    W[52] = w[52];
    W[53] = w[53];
    float b0 = bias[0], b1 = bias[1];

    float acc0[2][8], acc1[2][8];
#pragma unroll
    for (int r = 0; r < 2; ++r)
#pragma unroll
        for (int j = 0; j < 8; ++j) { acc0[r][j] = b0; acc1[r][j] = b1; }

    const float* xb = x + (size_t)b * 3 * HW;
#pragma unroll
    for (int ci = 0; ci < 3; ++ci) {
        const float* xc = xb + ci * HW;
#pragma unroll
        for (int iy = 0; iy < 4; ++iy) {
            int yy = y0 - 1 + iy;
            if (yy < 0 || yy >= HH) continue;   // uniform
            const float* r = xc + yy * WW;
            float4 cA = *(const float4*)(r + xs);
            float4 cB = *(const float4*)(r + xs + 4);
            float l  = (xs > 0)      ? r[xs - 1] : 0.f;
            float rr = (xs < WW - 8) ? r[xs + 8] : 0.f;
            float v[10] = {l, cA.x, cA.y, cA.z, cA.w,
                           cB.x, cB.y, cB.z, cB.w, rr};
#pragma unroll
            for (int orow = 0; orow < 2; ++orow) {
                int kh = iy - orow;
                if (kh < 0 || kh > 2) continue;
                float w00 = W[ci * 9 + kh * 3 + 0];
                float w01 = W[ci * 9 + kh * 3 + 1];
                float w02 = W[ci * 9 + kh * 3 + 2];
                float w10 = W[27 + ci * 9 + kh * 3 + 0];
                float w11 = W[27 + ci * 9 + kh * 3 + 1];
                float w12 = W[27 + ci * 9 + kh * 3 + 2];
#pragma unroll
                for (int j = 0; j < 8; ++j) {
                    acc0[orow][j] = fmaf(w00, v[j],
                                    fmaf(w01, v[j + 1],
                                    fmaf(w02, v[j + 2], acc0[orow][j])));
                    acc1[orow][j] = fmaf(w10, v[j],
                                    fmaf(w11, v[j + 1],
                                    fmaf(w12, v[j + 2], acc1[orow][j])));
                }
            }
        }
    }
#pragma unroll
    for (int orow = 0; orow < 2; ++orow) {
        size_t o = (size_t)b * HW + (size_t)(y0 + orow) * WW + xs;
        half8v h0, h1, hq;
#pragma unroll
        for (int j = 0; j < 8; ++j) {
            float du = acc1[orow][j] - acc0[orow][j];
            h0[j] = (half_t)acc0[orow][j];
            h1[j] = (half_t)du;
            hq[j] = (half_t)sig1(du);
        }
        *(half8v*)(u0p + o) = h0;
        *(half8v*)(dup + o) = h1;
        *(half8v*)(q0p + o) = hq;
    }
}

// ---------------------------------------------------------------------------
// Kernel 2: one CRF iteration in q-space, 4-row tiles (grid 2048 -> 8
// blocks/CU = 32 waves/CU, 100% occupancy). In q-space halo amplification
// costs only extra L2 half2 reads (14 rows per 4 own) — fma/sigmoid per own
// row is constant, unlike round-5's d-space attempt.
//   m = blur(q);  d' = du + 2*m - Sx*Sy;  q' = sigmoid(d')
// ---------------------------------------------------------------------------
__global__ __launch_bounds__(256) void q_iter(
    const half_t* __restrict__ qp, const half_t* __restrict__ dup,
    half_t* __restrict__ qnxt)
{
    __shared__ half_t v[4][528];   // zeros [0,6), data at 6+px, zeros [518,524)

    int bid  = blockIdx.x;
    int tile = (bid & 7) * 256 + (bid >> 3);   // grid 2048, bijective
    int b    = tile >> 7;                      // 128 tiles / image
    int y0   = (tile & 127) << 2;              // 4 output rows
    int tid  = threadIdx.x;
    int x0   = tid << 1;                       // 2 px per thread

    if (tid < 6) {
#pragma unroll
        for (int r = 0; r < 4; ++r) {
            v[r][tid] = (half_t)0.f;
            v[r][518 + tid] = (half_t)0.f;
        }
    }

    size_t pb = (size_t)b * HW + x0;

    half2v acc[4];
#pragma unroll
    for (int r = 0; r < 4; ++r) acc[r] = half2v{(half_t)0.f, (half_t)0.f};

#pragma unroll
    for (int i = 0; i < 14; ++i) {             // input rows y0-5 .. y0+8
        int yy = y0 + i - 5;
        if (yy < 0 || yy >= HH) continue;      // uniform
        half2v qv = *(const half2v*)(qp + pb + (size_t)yy * WW);
#pragma unroll
        for (int r = 0; r < 4; ++r) {
            int dt = i - r;
            if (dt < 0 || dt > 10) continue;   // compile-time
            half_t kh = (half_t)GK[dt];
            half2v kv = half2v{kh, kh};
            acc[r] = hfma2(kv, qv, acc[r]);
        }
    }
#pragma unroll
    for (int r = 0; r < 4; ++r)
        *(half2v*)(&v[r][6 + x0]) = acc[r];    // 4B-aligned ds_write_b32
    __syncthreads();

    float SxA = edgeS(x0), SxB = edgeS(x0 + 1);

#pragma unroll
    for (int r = 0; r < 4; ++r) {
        int yy = y0 + r;
        float Sy = edgeS(yy);

        half2v m01h = hblur_pk(&v[r][0], tid);
        float m0 = (float)m01h[0], m1 = (float)m01h[1];

        size_t po = pb + (size_t)yy * WW;
        half2v duv = *(const half2v*)(dup + po);
        float d0 = (float)duv[0] + fmaf(2.f, m0, -(SxA * Sy));
        float d1 = (float)duv[1] + fmaf(2.f, m1, -(SxB * Sy));

        half2v hq;
        hq[0] = (half_t)sig1(d0);
        hq[1] = (half_t)sig1(d1);
        *(half2v*)(qnxt + po) = hq;
    }
}

// ---------------------------------------------------------------------------
// Kernel 3: final blur of q4 + epilogue (fp32 NCHW out), 4-row tiles.
//   m = blur(q4); out0 = u0 + S - m ; out1 = u0 + du + m
// ---------------------------------------------------------------------------
__global__ __launch_bounds__(256) void q_final(
    const half_t* __restrict__ qp, const half_t* __restrict__ dup,
    const half_t* __restrict__ u0p, float* __restrict__ outp)
{
    __shared__ half_t v[4][528];

    int bid  = blockIdx.x;
    int tile = (bid & 7) * 256 + (bid >> 3);   // grid 2048, bijective
    int b    = tile >> 7;
    int y0   = (tile & 127) << 2;
    int tid  = threadIdx.x;
    int x0   = tid << 1;

    if (tid < 6) {
#pragma unroll
        for (int r = 0; r < 4; ++r) {
            v[r][tid] = (half_t)0.f;
            v[r][518 + tid] = (half_t)0.f;
        }
    }

    size_t pb = (size_t)b * HW + x0;

    half2v acc[4];
#pragma unroll
    for (int r = 0; r < 4; ++r) acc[r] = half2v{(half_t)0.f, (half_t)0.f};

#pragma unroll
    for (int i = 0; i < 14; ++i) {             // input rows y0-5 .. y0+8
        int yy = y0 + i - 5;
        if (yy < 0 || yy >= HH) continue;      // uniform
        half2v qv = *(const half2v*)(qp + pb + (size_t)yy * WW);
#pragma unroll
        for (int r = 0; r < 4; ++r) {
            int dt = i - r;
            if (dt < 0 || dt > 10) continue;   // compile-time
            half_t kh = (half_t)GK[dt];
            half2v kv = half2v{kh, kh};
            acc[r] = hfma2(kv, qv, acc[r]);
        }
    }
#pragma unroll
    for (int r = 0; r < 4; ++r)
        *(half2v*)(&v[r][6 + x0]) = acc[r];
    __syncthreads();

    float SxA = edgeS(x0), SxB = edgeS(x0 + 1);

#pragma unroll
    for (int r = 0; r < 4; ++r) {
        int yy = y0 + r;
        float Sy = edgeS(yy);

        half2v m01h = hblur_pk(&v[r][0], tid);
        float m0 = (float)m01h[0], m1 = (float)m01h[1];

        size_t po = pb + (size_t)yy * WW;
        half2v duv = *(const half2v*)(dup + po);
        half2v u0v = *(const half2v*)(u0p + po);
        float dua = (float)duv[0], dub = (float)duv[1];
        float ua  = (float)u0v[0], ub  = (float)u0v[1];

        float S0 = SxA * Sy, S1 = SxB * Sy;
        size_t oo = (size_t)b * 2 * HW + (size_t)yy * WW + x0;
        *(float2*)(outp + oo)      = make_float2(ua + (S0 - m0),
                                                 ub + (S1 - m1));
        *(float2*)(outp + oo + HW) = make_float2((ua + dua) + m0,
                                                 (ub + dub) + m1);
    }
}

extern "C" void kernel_launch(void* const* d_in, const int* in_sizes, int n_in,
                              void* d_out, int out_size, void* d_ws, size_t ws_size,
                              hipStream_t stream) {
    const float* x    = (const float*)d_in[0];   // (16,3,512,512)
    const float* w    = (const float*)d_in[1];   // (2,3,3,3)
    const float* bias = (const float*)d_in[2];   // (2,)

    float*  out = (float*)d_out;                 // (16,2,512,512) fp32
    half_t* u0p = (half_t*)d_ws;                 // 8.4 MB
    half_t* dup = u0p + NP1;                     // 8.4 MB
    half_t* qA  = dup + NP1;                     // 8.4 MB
    half_t* qB  = qA + NP1;                      // 8.4 MB

    conv3x3_duq<<<1024, 256, 0, stream>>>(x, w, bias, u0p, dup, qA);  // q0
    q_iter<<<2048, 256, 0, stream>>>(qA, dup, qB);                    // q1
    q_iter<<<2048, 256, 0, stream>>>(qB, dup, qA);                    // q2
    q_iter<<<2048, 256, 0, stream>>>(qA, dup, qB);                    // q3
    q_iter<<<2048, 256, 0, stream>>>(qB, dup, qA);                    // q4
    q_final<<<2048, 256, 0, stream>>>(qA, dup, u0p, out);             // out
}